// Round 7
// baseline (1896.540 us; speedup 1.0000x reference)
//
#include <hip/hip_runtime.h>

// ---------------------------------------------------------------------------
// GRU (T=256, B=1024, IN=128, H=256) + per-step BatchNorm, MI355X.
// R6->R7: ALL 64 folded-weight tiles per wave pinned in AGPRs (256 AGPRs;
// RF capacity: 512 KB/SIMD, 2 waves/SIMD -> 1024 regs/wave budget, 512 HW
// max, we use ~390). Removes R6's per-step 128 KB/CU L2 stream AND the
// 16 KB/wave/step LDS weight reads. K-loop = 8 ds_read_b128 + 64 MFMA.
// The "+a" asm pin is the proven mechanism (R6: VGPR 64->128, -0.5 ms).
// ---------------------------------------------------------------------------

typedef _Float16 half8 __attribute__((ext_vector_type(8)));
typedef float floatx4 __attribute__((ext_vector_type(4)));
typedef unsigned uintx4 __attribute__((ext_vector_type(4)));

#define EPS_BN 1e-5f

// ws layout (bytes):
//   [0,       524288)   wc: folded gate weights, 16 cgs x 32 tiles x 1 KB
//   [524288, 1114112)   w0: step-0 weights, 16 cgs x 36 tiles x 1 KB
//   [1114112,1179648)   wl: W_lin B-frags, 64 tiles x 1 KB
//   [1179648,1183744)   bias0: 256 x float4
//   [1183744,1187840)   bc: 256 x float4 folded biases
//   [1187840,1449984)   stats: 256 t x 128 c x {sum,sumsq} fp32 (memset 0)
#define WS_WC 0
#define WS_W0 524288
#define WS_WL 1114112
#define WS_B0 1179648
#define WS_BC 1183744
#define WS_ST 1187840

static __device__ __forceinline__ unsigned short f2h(float f) {
    union { _Float16 h; unsigned short u; } v;
    v.h = (_Float16)f;                      // v_cvt_f16_f32, RNE
    return v.u;
}
static __device__ __forceinline__ half8 as_h8(uint4 v) {
    union { uint4 u; half8 h; } x; x.u = v; return x.h;
}
// Load a 16B weight fragment and force it into AGPRs (opaque, non-remat).
static __device__ __forceinline__ half8 ld_agpr(const uint4* p) {
    uintx4 v = *(const uintx4*)p;
    asm volatile("; wpin" : "+a"(v));
    union { uintx4 u; half8 h; } x; x.u = v; return x.h;
}
static __device__ __forceinline__ float sigm(float x) {
    return 1.0f / (1.0f + __expf(-x));
}
static __device__ __forceinline__ float tanh_fast(float x) {
    return 1.0f - 2.0f / (__expf(2.0f * x) + 1.0f);
}
#define MFMA16(A, B, C) __builtin_amdgcn_mfma_f32_16x16x32_f16((A), (B), (C), 0, 0, 0)

// ---------------------------------------------------------------------------
// pack_w0: original weights -> fp16 B-frag tiles + wl + bias0. (R3-verified)
// B-frag 16x16x32: lane l holds B[n0+(l&15)][k0+(l>>4)*8+j].
// ---------------------------------------------------------------------------
__global__ void pack_w0_kernel(const float* __restrict__ W_ih, const float* __restrict__ W_hh,
                               const float* __restrict__ W_lin, const float* __restrict__ b_ih,
                               const float* __restrict__ b_hh,
                               uint4* __restrict__ w0, uint4* __restrict__ wl,
                               float4* __restrict__ bias0)
{
    int i = blockIdx.x * 256 + threadIdx.x;
    if (i < 36864) {                       // 576 w0 tiles x 64 lanes
        int lane = i & 63, tile = i >> 6;
        int w = tile / 36, rem = tile - w * 36;
        int g = rem / 12, kt = rem - g * 12;
        int n = g * 256 + (w << 4) + (lane & 15);
        int k0 = (kt << 5) + ((lane >> 4) << 3);
        const float* p = (k0 < 128) ? (W_ih + n * 128 + k0)
                                    : (W_hh + n * 256 + (k0 - 128));
        unsigned short h[8];
        #pragma unroll
        for (int j = 0; j < 8; ++j) h[j] = f2h(p[j]);
        uint4 v;
        v.x = (unsigned)h[0] | ((unsigned)h[1] << 16);
        v.y = (unsigned)h[2] | ((unsigned)h[3] << 16);
        v.z = (unsigned)h[4] | ((unsigned)h[5] << 16);
        v.w = (unsigned)h[6] | ((unsigned)h[7] << 16);
        w0[i] = v;
    } else if (i < 40960) {                // 64 wl tiles x 64 lanes
        int i2 = i - 36864;
        int lane = i2 & 63, tile = i2 >> 6;        // tile = nt*8 + kt
        int n = (tile >> 3) * 16 + (lane & 15);
        int k0 = ((tile & 7) << 5) + ((lane >> 4) << 3);
        const float* p = W_lin + n * 256 + k0;
        unsigned short h[8];
        #pragma unroll
        for (int j = 0; j < 8; ++j) h[j] = f2h(p[j]);
        uint4 v;
        v.x = (unsigned)h[0] | ((unsigned)h[1] << 16);
        v.y = (unsigned)h[2] | ((unsigned)h[3] << 16);
        v.z = (unsigned)h[4] | ((unsigned)h[5] << 16);
        v.w = (unsigned)h[6] | ((unsigned)h[7] << 16);
        wl[i2] = v;
    } else if (i < 41216) {
        int cb = i - 40960;
        bias0[cb] = make_float4(b_ih[cb] + b_hh[cb],
                                b_ih[256 + cb] + b_hh[256 + cb],
                                b_ih[512 + cb], b_hh[512 + cb]);
    }
}

// ---------------------------------------------------------------------------
// pack_wc: folded weights (fp32 fold, one fp16 round) + folded biases.
// tile idx = cg*32 + g*8 + kt; g: 0=r (W_ih_r@W_lin + W_hh_r), 1=z,
// 2=in (W_ihn@W_lin), 3=hn (W_hhn). (R5-verified)
// ---------------------------------------------------------------------------
__global__ void pack_wc_kernel(const float* __restrict__ W_ih, const float* __restrict__ W_hh,
                               const float* __restrict__ W_lin, const float* __restrict__ b_ih,
                               const float* __restrict__ b_hh, const float* __restrict__ b_lin,
                               uint4* __restrict__ wc, float4* __restrict__ bc)
{
    int i = blockIdx.x * 256 + threadIdx.x;
    if (i < 32768) {                       // 512 wc tiles x 64 lanes
        int lane = i & 63, tile = i >> 6;
        int w = tile >> 5, r = tile & 31;
        int g = r >> 3, kt = r & 7;
        int c = (w << 4) + (lane & 15);
        int k0 = (kt << 5) + ((lane >> 4) << 3);
        float s[8];
        if (g == 3) {
            #pragma unroll
            for (int j = 0; j < 8; ++j) s[j] = W_hh[(512 + c) * 256 + k0 + j];
        } else {
            int row = g * 256 + c;
            const float* wi = W_ih + row * 128;
            #pragma unroll
            for (int j = 0; j < 8; ++j) s[j] = 0.0f;
            for (int ii = 0; ii < 128; ++ii) {
                float wv = wi[ii];
                const float* wrow = W_lin + ii * 256 + k0;
                #pragma unroll
                for (int j = 0; j < 8; ++j) s[j] += wv * wrow[j];
            }
            if (g < 2) {
                #pragma unroll
                for (int j = 0; j < 8; ++j) s[j] += W_hh[row * 256 + k0 + j];
            }
        }
        unsigned short h[8];
        #pragma unroll
        for (int j = 0; j < 8; ++j) h[j] = f2h(s[j]);
        uint4 v;
        v.x = (unsigned)h[0] | ((unsigned)h[1] << 16);
        v.y = (unsigned)h[2] | ((unsigned)h[3] << 16);
        v.z = (unsigned)h[4] | ((unsigned)h[5] << 16);
        v.w = (unsigned)h[6] | ((unsigned)h[7] << 16);
        wc[i] = v;
    } else if (i < 33024) {
        int c = i - 32768;
        float d0 = 0.f, d1 = 0.f, d2 = 0.f;
        for (int ii = 0; ii < 128; ++ii) {
            float bl = b_lin[ii];
            d0 += bl * W_ih[c * 128 + ii];
            d1 += bl * W_ih[(256 + c) * 128 + ii];
            d2 += bl * W_ih[(512 + c) * 128 + ii];
        }
        bc[c] = make_float4(b_ih[c] + b_hh[c] + d0,
                            b_ih[256 + c] + b_hh[256 + c] + d1,
                            b_ih[512 + c] + d2,
                            b_hh[512 + c]);
    }
}

// ---------------------------------------------------------------------------
// Recurrence: 64 blocks x 512 thr (8 waves, 2/SIMD). Block owns 16 batch
// rows; wave w owns col-groups {w, w+8}. ALL 64 weight tiles AGPR-pinned.
// LDS (uint4 units): [0,1024) h-frag dbuf | [1024,1280) xbuf. 20 KB.
// One barrier per step; K-loop = 8 ds_read_b128 + 64 MFMA.
// ---------------------------------------------------------------------------
__global__ __launch_bounds__(512, 2) void gru_kernel(
    const float* __restrict__ inputs,
    const float* __restrict__ hidden,
    const uint4* __restrict__ wc,
    const uint4* __restrict__ w0,
    const float4* __restrict__ bias0,
    const float4* __restrict__ bcp,
    float* __restrict__ out)
{
    __shared__ uint4 lds[1280];            // 20480 B

    const int tid  = threadIdx.x;
    const int lane = tid & 63;
    const int w    = tid >> 6;             // wave 0..7
    const int quad = lane >> 4;
    const int nc   = lane & 15;
    const int r0   = blockIdx.x << 4;
    const int c0   = (w << 4) + nc;
    const int c1   = 128 + c0;
    const float4 bc0 = bcp[c0];
    const float4 bc1 = bcp[c1];
    const uint4* wcw0 = wc + (size_t)w * 2048;        // 32 tiles * 64
    const uint4* wcw1 = wc + (size_t)(w + 8) * 2048;

    // ---- AGPR-pinned tiles: ALL of r, z, in, hn for both col-groups
    half8 wr0[8], wz0[8], wi0[8], wh0[8];
    half8 wr1[8], wz1[8], wi1[8], wh1[8];
    #pragma unroll
    for (int kt = 0; kt < 8; ++kt) {
        wr0[kt] = ld_agpr(&wcw0[kt * 64 + lane]);
        wz0[kt] = ld_agpr(&wcw0[(8 + kt) * 64 + lane]);
        wi0[kt] = ld_agpr(&wcw0[(16 + kt) * 64 + lane]);
        wh0[kt] = ld_agpr(&wcw0[(24 + kt) * 64 + lane]);
        wr1[kt] = ld_agpr(&wcw1[kt * 64 + lane]);
        wz1[kt] = ld_agpr(&wcw1[(8 + kt) * 64 + lane]);
        wi1[kt] = ld_agpr(&wcw1[(16 + kt) * 64 + lane]);
        wh1[kt] = ld_agpr(&wcw1[(24 + kt) * 64 + lane]);
    }

    // fp32 master hidden state: rows quad*4+d; [0..3]=c0, [4..7]=c1
    float hreg[8];
    #pragma unroll
    for (int d = 0; d < 4; ++d) {
        hreg[d]     = hidden[(r0 + (quad << 2) + d) * 256 + c0];
        hreg[4 + d] = hidden[(r0 + (quad << 2) + d) * 256 + c1];
    }

    // A-frag write addressing: A[m][k]: kt=k>>5, k'=k&31,
    // frag lane=(k'>>3)*16+m, j=k'&7; u16 idx=(kt*64+lane_f)*8+j
    unsigned short* lds_u16 = (unsigned short*)lds;
    const int kp  = ((w & 1) << 4) + nc;
    const int lf  = ((kp >> 3) << 4) + (quad << 2);
    const int hfb0 = (((w >> 1) * 64 + lf) << 3) + (kp & 7);
    const int hfb1 = (((4 + (w >> 1)) * 64 + lf) << 3) + (kp & 7);

    // init h(0) frags -> buf0
    for (int idx = tid; idx < 2048; idx += 512) {
        int ktl = idx >> 8;
        int rem = idx & 255;
        int lfr = rem >> 2, jg = rem & 3;
        int m = lfr & 15;
        int hc = ktl * 32 + (lfr >> 4) * 8 + jg * 2;
        const float* p = hidden + (r0 + m) * 256 + hc;
        unsigned pk = (unsigned)f2h(p[0]) | ((unsigned)f2h(p[1]) << 16);
        ((unsigned*)lds)[(ktl * 64 + lfr) * 4 + jg] = pk;
    }
    // init x frags -> xbuf
    for (int idx = tid; idx < 1024; idx += 512) {
        int kt = idx >> 8, lfr = (idx >> 2) & 63, jg = idx & 3;
        int m = lfr & 15;
        int k0 = (kt << 5) + ((lfr >> 4) << 3) + (jg << 1);
        const float* p = inputs + (r0 + m) * 128 + k0;
        unsigned pk = (unsigned)f2h(p[0]) | ((unsigned)f2h(p[1]) << 16);
        ((unsigned*)lds)[(1024 + (kt << 6) + lfr) * 4 + jg] = pk;
    }
    __syncthreads();

    unsigned short* Hout = (unsigned short*)out;

    // ---- t = 0: K=384 on [x|h] with original w0 (streamed once)
    {
        #pragma unroll
        for (int g2 = 0; g2 < 2; ++g2) {
            const uint4* ww = w0 + (size_t)(g2 ? (w + 8) : w) * 2304;  // 36*64
            floatx4 ar = {0.f,0.f,0.f,0.f}, az = {0.f,0.f,0.f,0.f};
            floatx4 ain = {0.f,0.f,0.f,0.f}, ahn = {0.f,0.f,0.f,0.f};
            #pragma unroll
            for (int kt = 0; kt < 12; ++kt) {
                half8 A = as_h8(kt < 4 ? lds[1024 + (kt << 6) + lane]
                                       : lds[((kt - 4) << 6) + lane]);
                ar = MFMA16(A, as_h8(ww[kt * 64 + lane]), ar);
                az = MFMA16(A, as_h8(ww[(12 + kt) * 64 + lane]), az);
                if (kt < 4)
                    ain = MFMA16(A, as_h8(ww[(24 + kt) * 64 + lane]), ain);
                else
                    ahn = MFMA16(A, as_h8(ww[(24 + kt) * 64 + lane]), ahn);
            }
            const int cc = g2 ? c1 : c0;
            const int hfb = g2 ? hfb1 : hfb0;
            float4 b0 = bias0[cc];
            #pragma unroll
            for (int d = 0; d < 4; ++d) {
                float rr = sigm(ar[d] + b0.x);
                float zz = sigm(az[d] + b0.y);
                float nn = tanh_fast(ain[d] + b0.z + rr * (ahn[d] + b0.w));
                float hnew = (1.0f - zz) * nn + zz * hreg[(g2 << 2) + d];
                hreg[(g2 << 2) + d] = hnew;
                unsigned short hu = f2h(hnew);
                lds_u16[4096 + hfb + (d << 3)] = hu;      // buf1
                Hout[((size_t)(r0 + (quad << 2) + d) << 8) + cc] = hu;
            }
        }
        __syncthreads();
    }

    for (int t = 1; t < 256; ++t) {
        const int rb   = (t & 1) << 9;                 // read buf (uint4)
        const int wb16 = (((t + 1) & 1) << 9) << 3;    // write buf (u16)

        floatx4 ar0 = {0.f,0.f,0.f,0.f}, az0 = {0.f,0.f,0.f,0.f};
        floatx4 ai0 = {0.f,0.f,0.f,0.f}, ah0 = {0.f,0.f,0.f,0.f};
        floatx4 ar1 = {0.f,0.f,0.f,0.f}, az1 = {0.f,0.f,0.f,0.f};
        floatx4 ai1 = {0.f,0.f,0.f,0.f}, ah1 = {0.f,0.f,0.f,0.f};

        #pragma unroll
        for (int kt = 0; kt < 8; ++kt) {
            half8 A = as_h8(lds[rb + (kt << 6) + lane]);
            ar0 = MFMA16(A, wr0[kt], ar0);
            ar1 = MFMA16(A, wr1[kt], ar1);
            az0 = MFMA16(A, wz0[kt], az0);
            az1 = MFMA16(A, wz1[kt], az1);
            ai0 = MFMA16(A, wi0[kt], ai0);
            ai1 = MFMA16(A, wi1[kt], ai1);
            ah0 = MFMA16(A, wh0[kt], ah0);
            ah1 = MFMA16(A, wh1[kt], ah1);
        }

        const size_t obase = (size_t)t * 1024 + r0 + (quad << 2);
        #pragma unroll
        for (int d = 0; d < 4; ++d) {
            float rr = sigm(ar0[d] + bc0.x);
            float zz = sigm(az0[d] + bc0.y);
            float nn = tanh_fast(ai0[d] + bc0.z + rr * (ah0[d] + bc0.w));
            float hnew = (1.0f - zz) * nn + zz * hreg[d];
            hreg[d] = hnew;
            unsigned short hu = f2h(hnew);
            lds_u16[wb16 + hfb0 + (d << 3)] = hu;
            Hout[((obase + d) << 8) + c0] = hu;
        }
        #pragma unroll
        for (int d = 0; d < 4; ++d) {
            float rr = sigm(ar1[d] + bc1.x);
            float zz = sigm(az1[d] + bc1.y);
            float nn = tanh_fast(ai1[d] + bc1.z + rr * (ah1[d] + bc1.w));
            float hnew = (1.0f - zz) * nn + zz * hreg[4 + d];
            hreg[4 + d] = hnew;
            unsigned short hu = f2h(hnew);
            lds_u16[wb16 + hfb1 + (d << 3)] = hu;
            Hout[((obase + d) << 8) + c1] = hu;
        }
        __syncthreads();
    }
}

// ---------------------------------------------------------------------------
// y-GEMM: out[t,b,:] = H[t,b,:] @ W_lin^T + b_lin, fused BN partial sums.
// In-place over d_out (stages its 16 H-rows to LDS first). (R5-verified)
// ---------------------------------------------------------------------------
__global__ __launch_bounds__(256) void ygemm_kernel(
    const uint4* __restrict__ wl, const float* __restrict__ b_lin,
    float* __restrict__ out, float* __restrict__ stats)
{
    __shared__ unsigned short sh[16 * 264];
    const int tid = threadIdx.x;
    const int t = blockIdx.x >> 6;
    const int r0 = (blockIdx.x & 63) << 4;

    {
        int row = tid >> 4, seg = tid & 15;
        const uint4* src = (const uint4*)((const unsigned short*)out
                         + (((size_t)t << 10) + r0 + row) * 256) + (seg << 1);
        uint4 a = src[0], b = src[1];
        uint4* dst = (uint4*)(sh + row * 264 + (seg << 4));
        dst[0] = a; dst[1] = b;
    }
    __syncthreads();

    const int lane = tid & 63, w = tid >> 6;
    const int quad = lane >> 4, nc = lane & 15;
    const int m = lane & 15, khi = lane >> 4;

    half8 B0[8], B1[8];
    #pragma unroll
    for (int kt = 0; kt < 8; ++kt) {
        B0[kt] = as_h8(wl[(((w << 1) + 0) * 8 + kt) * 64 + lane]);
        B1[kt] = as_h8(wl[(((w << 1) + 1) * 8 + kt) * 64 + lane]);
    }
    floatx4 a0 = {0.f,0.f,0.f,0.f}, a1 = {0.f,0.f,0.f,0.f};
    #pragma unroll
    for (int kt = 0; kt < 8; ++kt) {
        half8 A = *(const half8*)(sh + m * 264 + (kt << 5) + (khi << 3));
        a0 = MFMA16(A, B0[kt], a0);
        a1 = MFMA16(A, B1[kt], a1);
    }
    #pragma unroll
    for (int g = 0; g < 2; ++g) {
        floatx4 acc = g ? a1 : a0;
        int i = (((w << 1) + g) << 4) + nc;
        float bl = b_lin[i];
        float s1 = 0.f, s2 = 0.f;
        float* orow = out + (((size_t)t << 10) + r0 + (quad << 2)) * 128 + i;
        #pragma unroll
        for (int d = 0; d < 4; ++d) {
            float y = acc[d] + bl;
            orow[(size_t)d << 7] = y;
            s1 += y; s2 += y * y;
        }
        s1 += __shfl_xor(s1, 16); s1 += __shfl_xor(s1, 32);
        s2 += __shfl_xor(s2, 16); s2 += __shfl_xor(s2, 32);
        if (lane < 16) {
            int si = ((t << 7) + (((w << 1) + g) << 4) + lane) << 1;
            atomicAdd(&stats[si], s1);
            atomicAdd(&stats[si + 1], s2);
        }
    }
}

// ---------------------------------------------------------------------------
// Normalize: in-place BN from raw sums. Biased variance, eps inside sqrt.
// ---------------------------------------------------------------------------
__global__ void norm_kernel(float* __restrict__ out, const float* __restrict__ stats)
{
    __shared__ float smean[128], sscale[128];
    int t = blockIdx.x >> 2, q = blockIdx.x & 3;
    int tid = threadIdx.x;
    if (tid < 128) {
        int si = ((t << 7) + tid) << 1;
        float mean = stats[si] * (1.0f / 1024.0f);
        float var = stats[si + 1] * (1.0f / 1024.0f) - mean * mean;
        smean[tid] = mean;
        sscale[tid] = rsqrtf(var + EPS_BN);
    }
    __syncthreads();
    float4* p = (float4*)(out + ((size_t)t << 17) + ((size_t)q << 15));
    for (int i = tid; i < 8192; i += 256) {
        int cc = (i & 31) << 2;
        float4 v = p[i];
        v.x = (v.x - smean[cc])     * sscale[cc];
        v.y = (v.y - smean[cc + 1]) * sscale[cc + 1];
        v.z = (v.z - smean[cc + 2]) * sscale[cc + 2];
        v.w = (v.w - smean[cc + 3]) * sscale[cc + 3];
        p[i] = v;
    }
}

extern "C" void kernel_launch(void* const* d_in, const int* in_sizes, int n_in,
                              void* d_out, int out_size, void* d_ws, size_t ws_size,
                              hipStream_t stream) {
    (void)in_sizes; (void)n_in; (void)out_size; (void)ws_size;
    const float* inputs = (const float*)d_in[0];
    const float* hidden = (const float*)d_in[1];
    const float* W_ih   = (const float*)d_in[2];
    const float* b_ih   = (const float*)d_in[3];
    const float* W_hh   = (const float*)d_in[4];
    const float* b_hh   = (const float*)d_in[5];
    const float* W_lin  = (const float*)d_in[6];
    const float* b_lin  = (const float*)d_in[7];

    char* ws = (char*)d_ws;
    uint4*  wcp   = (uint4*)(ws + WS_WC);
    uint4*  w0p   = (uint4*)(ws + WS_W0);
    uint4*  wlp   = (uint4*)(ws + WS_WL);
    float4* bias0 = (float4*)(ws + WS_B0);
    float4* bcp   = (float4*)(ws + WS_BC);
    float*  stats = (float*)(ws + WS_ST);

    hipMemsetAsync(stats, 0, 262144, stream);
    pack_w0_kernel<<<161, 256, 0, stream>>>(W_ih, W_hh, W_lin, b_ih, b_hh, w0p, wlp, bias0);
    pack_wc_kernel<<<129, 256, 0, stream>>>(W_ih, W_hh, W_lin, b_ih, b_hh, b_lin, wcp, bcp);
    gru_kernel<<<64, 512, 0, stream>>>(inputs, hidden, wcp, w0p, bias0, bcp, (float*)d_out);
    ygemm_kernel<<<16384, 256, 0, stream>>>(wlp, b_lin, (float*)d_out, stats);
    norm_kernel<<<1024, 256, 0, stream>>>((float*)d_out, stats);
}